// Round 15
// baseline (735.836 us; speedup 1.0000x reference)
//
#include <hip/hip_runtime.h>
#include <hip/hip_fp16.h>
#include <math.h>

#define NN 50000
#define NE 600000
#define DIN 32
#define DD 128
#define NL 3
#define NC 4

__device__ __forceinline__ float clip50(float x) { return fminf(fmaxf(x, -50.f), 50.f); }

typedef __attribute__((ext_vector_type(8))) short bf16x8;
typedef __attribute__((ext_vector_type(4))) float f32x4;
typedef __attribute__((ext_vector_type(4))) unsigned int u32x4;

__device__ __forceinline__ unsigned short f2bf(float f) {
  unsigned u = __float_as_uint(f);
  return (unsigned short)((u + 0x7fffu + ((u >> 16) & 1u)) >> 16);
}

__device__ __forceinline__ float2 h2f2(unsigned int w) {
  __half2 h;
  *(unsigned int*)&h = w;
  return __half22float2(h);
}

__device__ __forceinline__ unsigned int f2h2(float a, float b) {
  __half2 h = __floats2half2_rn(a, b);
  return *(unsigned int*)&h;
}

// ---------------- CSR build ----------------
__global__ void k_zero(int* __restrict__ deg, float* __restrict__ bn_acc) {
  int i = blockIdx.x * blockDim.x + threadIdx.x;
  if (i < NN) deg[i] = 0;
  if (i < 4 * 256) bn_acc[i] = 0.f;
}

__global__ void k_hist(const int* __restrict__ ei, int* __restrict__ deg) {
  int e = blockIdx.x * blockDim.x + threadIdx.x;
  if (e < NE) atomicAdd(&deg[ei[NE + e]], 1);
}

// 3-phase parallel scan
__global__ void k_scan1(const int* __restrict__ deg, int* __restrict__ fill,
                        int* __restrict__ btot) {
  __shared__ int sd[1024];
  int tid = threadIdx.x;
  int i = blockIdx.x * 1024 + tid;
  int v = (i < NN) ? deg[i] : 0;
  sd[tid] = v;
  __syncthreads();
  for (int off = 1; off < 1024; off <<= 1) {
    int t = (tid >= off) ? sd[tid - off] : 0;
    __syncthreads();
    sd[tid] += t;
    __syncthreads();
  }
  if (i < NN) fill[i] = sd[tid] - v;  // block-local exclusive
  if (tid == 1023) btot[blockIdx.x] = sd[1023];
}

__global__ void k_scan2(int* __restrict__ btot, int nb) {
  int tid = threadIdx.x;  // one wave of 64, nb <= 64
  int v = (tid < nb) ? btot[tid] : 0;
  int orig = v;
#pragma unroll
  for (int off = 1; off < 64; off <<= 1) {
    int t = __shfl_up(v, off, 64);
    if (tid >= off) v += t;
  }
  if (tid < nb) btot[tid] = v - orig;  // exclusive block offset
}

__global__ void k_scan3(const int* __restrict__ btot, int* __restrict__ fill,
                        int* __restrict__ rowptr) {
  int i = blockIdx.x * blockDim.x + threadIdx.x;
  if (i < NN) {
    int r = fill[i] + btot[i >> 10];
    rowptr[i] = r;
    fill[i] = r;
  }
  if (i == 0) rowptr[NN] = NE;
}

__global__ void k_scatter(const int* __restrict__ ei, int* __restrict__ fill,
                          int* __restrict__ perm_src) {
  int e = blockIdx.x * blockDim.x + threadIdx.x;
  if (e < NE) {
    int dst = ei[NE + e];
    int pos = atomicAdd(&fill[dst], 1);
    perm_src[pos] = ei[e];
  }
}

// ---------------- weight prep: transpose + split to bf16 hi/lo ----------------
// (wl kept for layout compatibility; 2-pass GEMM no longer reads it)
__global__ void k_wprep(const float* __restrict__ pWq, const float* __restrict__ pWk,
                        const float* __restrict__ pWv, const float* __restrict__ pWr,
                        const float* __restrict__ cWq, const float* __restrict__ cWk,
                        const float* __restrict__ cWv, const float* __restrict__ cWr,
                        unsigned short* __restrict__ wh, unsigned short* __restrict__ wl) {
  int mat = blockIdx.y;
  int K = (mat < 4) ? 32 : 128;
  int nel = K * 128;
  int idx = blockIdx.x * 256 + threadIdx.x;
  if (idx >= nel) return;
  int k = idx >> 7;
  int col = idx & 127;
  int m = (mat < 4) ? mat : ((mat - 4) & 3);
  int layer = (mat < 4) ? 0 : ((mat - 4) >> 2);
  const float* base;
  if (mat < 4)
    base = (m == 0) ? pWq : (m == 1) ? pWk : (m == 2) ? pWv : pWr;
  else
    base = ((m == 0) ? cWq : (m == 1) ? cWk : (m == 2) ? cWv : cWr) + (size_t)layer * 16384;
  float f = base[idx];  // [k][col] row-major
  size_t off = (mat < 4) ? (size_t)mat * 4096 : 16384 + (size_t)(mat - 4) * 16384;
  unsigned short h = f2bf(f);
  float lo = f - __uint_as_float((unsigned)h << 16);
  wh[off + (size_t)col * K + k] = h;
  wl[off + (size_t)col * K + k] = f2bf(lo);
}

// ---------------- MFMA GEMM, ONE MATRIX PER BLOCK, B(hi) staged in LDS ----------------
// R14 structure, 2-PASS split: acc = Ahi*Bh + Alo*Bh (exact-A x bf16-W).
// Dropped Ahi*Bl pass: error ~ A*Wl ~ 2^-9 rel (~0.002 abs), same class as fp16 storage.
// LDS halves (68->35KB) -> 4 blocks/CU (2x occupancy); MFMA work x2/3.
// blockIdx.y = matrix m (0:q->fp16 + hwr(fp16), 1:k->kv.x, 2:v->kv.y, 3:r->fp16).
// MODE 0: A raw fp32. MODE 1: A' = bn(A). MODE 2: A' = clip(bn(A)+ident fp16).
template <int KD, int MODE, typename TA>
__launch_bounds__(256)
__global__ void k_gemm_lds(const TA* __restrict__ A,
                           const float* __restrict__ bn_acc,
                           const float* __restrict__ bng,
                           const float* __restrict__ bnb,
                           const __half* __restrict__ ident,
                           __half* __restrict__ hwr,
                           const unsigned short* __restrict__ WH,
                           __half* __restrict__ Oq, __half* __restrict__ kv,
                           __half* __restrict__ Or) {
  constexpr int KS = KD / 32;
  constexpr int PK = KD + 8;
  constexpr int NTILES = (NN + 63) / 64;
  __shared__ unsigned short sBh[128 * PK];
  __shared__ float scoef[256];
  const int m = blockIdx.y;
  const unsigned short* wh = WH + (size_t)m * (KD * 128);
  for (int idx = threadIdx.x * 8; idx < 128 * KD; idx += 256 * 8) {
    int col = idx / KD, k = idx - col * KD;
    *(u32x4*)(&sBh[col * PK + k]) = *(const u32x4*)(wh + idx);
  }
  if constexpr (MODE > 0) {
    if (threadIdx.x < 128) {
      int c = threadIdx.x;
      float mean = bn_acc[c] * (1.f / NN);
      float var = bn_acc[128 + c] * (1.f / NN) - mean * mean;
      float sc = bng[c] * rsqrtf(var + 1e-5f);
      scoef[c] = sc;
      scoef[128 + c] = bnb[c] - mean * sc;
    }
  }
  __syncthreads();
  const int lane = threadIdx.x & 63;
  const int w = threadIdx.x >> 6;
  const int l15 = lane & 15;
  const int lhi = lane >> 4;
  for (int tile = blockIdx.x; tile < NTILES; tile += gridDim.x) {
    int row = tile * 64 + w * 16 + l15;
    bool rok = row < NN;
    int rowA = rok ? row : NN - 1;
    bf16x8 ahi[KS], alo[KS];
#pragma unroll
    for (int s = 0; s < KS; ++s) {
      int c0 = s * 32 + lhi * 8;
      float f[8];
      if constexpr (sizeof(TA) == 4) {
        const float* ap = (const float*)A + (size_t)rowA * KD + c0;
        float4 a0 = *(const float4*)(ap);
        float4 a1 = *(const float4*)(ap + 4);
        f[0] = a0.x; f[1] = a0.y; f[2] = a0.z; f[3] = a0.w;
        f[4] = a1.x; f[5] = a1.y; f[6] = a1.z; f[7] = a1.w;
      } else {
        const __half* ap = (const __half*)A + (size_t)rowA * KD + c0;
        u32x4 aw = *(const u32x4*)(ap);
#pragma unroll
        for (int j = 0; j < 4; ++j) {
          float2 t = h2f2(aw[j]);
          f[2 * j] = t.x;
          f[2 * j + 1] = t.y;
        }
      }
      if constexpr (MODE > 0) {
        float4 s0 = *(const float4*)(&scoef[c0]);
        float4 s1 = *(const float4*)(&scoef[c0 + 4]);
        float4 h0 = *(const float4*)(&scoef[128 + c0]);
        float4 h1 = *(const float4*)(&scoef[128 + c0 + 4]);
        float sc[8] = {s0.x, s0.y, s0.z, s0.w, s1.x, s1.y, s1.z, s1.w};
        float sh[8] = {h0.x, h0.y, h0.z, h0.w, h1.x, h1.y, h1.z, h1.w};
        if constexpr (MODE == 2) {
          const __half* ip = ident + (size_t)rowA * KD + c0;
          u32x4 iw = *(const u32x4*)(ip);
          float id[8];
#pragma unroll
          for (int j = 0; j < 4; ++j) {
            float2 t = h2f2(iw[j]);
            id[2 * j] = t.x;
            id[2 * j + 1] = t.y;
          }
#pragma unroll
          for (int j = 0; j < 8; ++j) f[j] = clip50(fmaf(f[j], sc[j], sh[j]) + id[j]);
        } else {
#pragma unroll
          for (int j = 0; j < 8; ++j) f[j] = fmaf(f[j], sc[j], sh[j]);
        }
        if (m == 0 && rok) {
          __half* hp = hwr + (size_t)row * KD + c0;
          u32x4 hw;
          hw[0] = f2h2(f[0], f[1]);
          hw[1] = f2h2(f[2], f[3]);
          hw[2] = f2h2(f[4], f[5]);
          hw[3] = f2h2(f[6], f[7]);
          *(u32x4*)(hp) = hw;
        }
      }
#pragma unroll
      for (int j = 0; j < 8; ++j) {
        unsigned short h = f2bf(f[j]);
        ahi[s][j] = (short)h;
        float lo = f[j] - __uint_as_float((unsigned)h << 16);
        alo[s][j] = (short)f2bf(lo);
      }
    }
#pragma unroll
    for (int ct = 0; ct < 8; ++ct) {
      f32x4 acc = {0.f, 0.f, 0.f, 0.f};
      int colB = ct * 16 + l15;
#pragma unroll
      for (int s = 0; s < KS; ++s) {
        int boff = colB * PK + s * 32 + lhi * 8;
        bf16x8 bh = *(const bf16x8*)(&sBh[boff]);
        acc = __builtin_amdgcn_mfma_f32_16x16x32_bf16(ahi[s], bh, acc, 0, 0, 0);
        acc = __builtin_amdgcn_mfma_f32_16x16x32_bf16(alo[s], bh, acc, 0, 0, 0);
      }
      int rbase = tile * 64 + w * 16 + lhi * 4;
      if (m == 0 || m == 3) {
        __half* O = (m == 0) ? Oq : Or;
#pragma unroll
        for (int j = 0; j < 4; ++j) {
          int g = rbase + j;
          if (g < NN) O[(size_t)g * 128 + colB] = __float2half(clip50(acc[j]));
        }
      } else {
        int sub = m - 1;
#pragma unroll
        for (int j = 0; j < 4; ++j) {
          int g = rbase + j;
          if (g < NN)
            kv[((size_t)g * 128 + colB) * 2 + sub] = __float2half(clip50(acc[j]));
        }
      }
    }
  }
}

// ---------------- conv (heads=4, D=128) + LN + ReLU + BN partial stats ----------------
#define LDKV(i, off)                                            \
  u32x4 kv##i = {0, 0, 0, 0};                                   \
  if (cnt > (off)) {                                            \
    int s##i = __shfl(myidx, lbase + b + (off), 64);            \
    kv##i = *(const u32x4*)(kvp + (size_t)s##i * 256 + 8 * sl); \
  }

#define EDKV(i, off)                                                              \
  if (cnt > (off)) {                                                              \
    float2 c0 = h2f2(kv##i[0]), c1 = h2f2(kv##i[1]);                              \
    float2 c2 = h2f2(kv##i[2]), c3 = h2f2(kv##i[3]);                              \
    float p = c0.x * q4.x + c1.x * q4.y + c2.x * q4.z + c3.x * q4.w;              \
    p += __shfl_xor(p, 1); p += __shfl_xor(p, 2); p += __shfl_xor(p, 4);          \
    float ex = __expf(clip50(p * scale));                                         \
    denom += ex;                                                                  \
    acc.x = fmaf(c0.y, ex, acc.x); acc.y = fmaf(c1.y, ex, acc.y);                 \
    acc.z = fmaf(c2.y, ex, acc.z); acc.w = fmaf(c3.y, ex, acc.w);                 \
  }

__launch_bounds__(256)
__global__ void k_conv128(const int* __restrict__ rowptr, const int* __restrict__ perm_src,
                          const __half* __restrict__ qb, const __half* __restrict__ kvp,
                          const __half* __restrict__ rb,
                          const float* __restrict__ lng, const float* __restrict__ lnb,
                          __half* __restrict__ hact, float* __restrict__ bn_acc) {
  const float scale = 0.17677669529663687f;  // 32^-0.5
  __shared__ float s_bn[256];
  int tid = threadIdx.x;
  if (tid < 256) s_bn[tid] = 0.f;
  __syncthreads();
  int sl = tid & 31;
  int lbase = tid & 32;
  int grp = tid >> 5;
  int gid = blockIdx.x * 8 + grp;
  int ng = gridDim.x * 8;
  float bs[4] = {0, 0, 0, 0}, bq[4] = {0, 0, 0, 0};
  float4 g4 = *(const float4*)(lng + 4 * sl);
  float4 b4 = *(const float4*)(lnb + 4 * sl);
  for (int node = gid; node < NN; node += ng) {
    int beg = rowptr[node], end = rowptr[node + 1];
    uint2 qw = *(const uint2*)(qb + (size_t)node * 128 + 4 * sl);
    float2 qlo = h2f2(qw.x), qhi = h2f2(qw.y);
    float4 q4 = make_float4(qlo.x, qlo.y, qhi.x, qhi.y);
    float denom = 0.f;
    float4 acc = make_float4(0.f, 0.f, 0.f, 0.f);
    for (int chunk = beg; chunk < end; chunk += 32) {
      int m = min(32, end - chunk);
      int myidx = (chunk + sl < end) ? perm_src[chunk + sl] : 0;  // coalesced
      for (int b = 0; b < m; b += 8) {
        int cnt = m - b;  // uniform within group
        LDKV(0, 0)
        LDKV(1, 1)
        LDKV(2, 2)
        LDKV(3, 3)
        LDKV(4, 4)
        LDKV(5, 5)
        LDKV(6, 6)
        LDKV(7, 7)
        EDKV(0, 0)
        EDKV(1, 1)
        EDKV(2, 2)
        EDKV(3, 3)
        EDKV(4, 4)
        EDKV(5, 5)
        EDKV(6, 6)
        EDKV(7, 7)
      }
    }
    float inv = 1.f / (denom + 1e-16f);
    uint2 rw = *(const uint2*)(rb + (size_t)node * 128 + 4 * sl);
    float2 rlo = h2f2(rw.x), rhi = h2f2(rw.y);
    float ox = fmaf(acc.x, inv, rlo.x), oy = fmaf(acc.y, inv, rlo.y);
    float oz = fmaf(acc.z, inv, rhi.x), ow = fmaf(acc.w, inv, rhi.y);
    float s = ox + oy + oz + ow;
#pragma unroll
    for (int off = 1; off < 32; off <<= 1) s += __shfl_xor(s, off);
    float mu = s * (1.f / 128.f);
    float dx = ox - mu, dy = oy - mu, dz = oz - mu, dw = ow - mu;
    float vv = dx * dx + dy * dy + dz * dz + dw * dw;
#pragma unroll
    for (int off = 1; off < 32; off <<= 1) vv += __shfl_xor(vv, off);
    float rstd = rsqrtf(vv * (1.f / 128.f) + 1e-5f);
    float y0 = fmaxf(fmaf(dx * rstd, g4.x, b4.x), 0.f);
    float y1 = fmaxf(fmaf(dy * rstd, g4.y, b4.y), 0.f);
    float y2 = fmaxf(fmaf(dz * rstd, g4.z, b4.z), 0.f);
    float y3 = fmaxf(fmaf(dw * rstd, g4.w, b4.w), 0.f);
    uint2 ho;
    ho.x = f2h2(y0, y1);
    ho.y = f2h2(y2, y3);
    *(uint2*)(hact + (size_t)node * 128 + 4 * sl) = ho;
    bs[0] += y0; bq[0] += y0 * y0; bs[1] += y1; bq[1] += y1 * y1;
    bs[2] += y2; bq[2] += y2 * y2; bs[3] += y3; bq[3] += y3 * y3;
  }
#pragma unroll
  for (int j = 0; j < 4; ++j) {
    atomicAdd(&s_bn[4 * sl + j], bs[j]);
    atomicAdd(&s_bn[128 + 4 * sl + j], bq[j]);
  }
  __syncthreads();
  if (tid < 256) atomicAdd(&bn_acc[tid], s_bn[tid]);
}

// ---------------- final projection GEMM: inline BN coef + fused BN+res+clip ----------------
__launch_bounds__(128)
__global__ void k_gemm_final(const __half* __restrict__ hact,
                             const float* __restrict__ bn_acc,
                             const float* __restrict__ bng, const float* __restrict__ bnb,
                             const __half* __restrict__ ident,
                             const float* __restrict__ Wq, const float* __restrict__ Wk,
                             const float* __restrict__ Wv, const float* __restrict__ Wr,
                             float* __restrict__ Oq, float* __restrict__ Ok,
                             float* __restrict__ Ov, float* __restrict__ Or) {
  __shared__ float At[32 * 130];
  __shared__ float scoef[256];
  {
    int c = threadIdx.x;  // block is 128 threads
    float mean = bn_acc[c] * (1.f / NN);
    float var = bn_acc[128 + c] * (1.f / NN) - mean * mean;
    float sc = bng[c] * rsqrtf(var + 1e-5f);
    scoef[c] = sc;
    scoef[128 + c] = bnb[c] - mean * sc;
  }
  __syncthreads();
  int row0 = blockIdx.x * 32;
  for (int idx = threadIdx.x; idx < 32 * 128; idx += 128) {
    int r = idx >> 7, k = idx & 127;
    int gr = row0 + r;
    float v = 0.f;
    if (gr < NN) {
      v = clip50(fmaf(__half2float(hact[(size_t)gr * 128 + k]), scoef[k], scoef[128 + k]) +
                 __half2float(ident[(size_t)gr * 128 + k]));
    }
    At[r * 130 + k] = v;
  }
  __syncthreads();
  int r = threadIdx.x >> 2, m = threadIdx.x & 3;
  const float* W = (m == 0) ? Wq : (m == 1) ? Wk : (m == 2) ? Wv : Wr;
  float4 acc = make_float4(0, 0, 0, 0);
  const float* Ab = &At[r * 130];
  for (int k = 0; k < 128; ++k) {
    float a = Ab[k];
    float4 w = *(const float4*)(W + k * 4);
    acc.x = fmaf(a, w.x, acc.x); acc.y = fmaf(a, w.y, acc.y);
    acc.z = fmaf(a, w.z, acc.z); acc.w = fmaf(a, w.w, acc.w);
  }
  int gr = row0 + r;
  if (gr < NN) {
    float* O = (m == 0) ? Oq : (m == 1) ? Ok : (m == 2) ? Ov : Or;
    *(float4*)(O + gr * 4) =
        make_float4(clip50(acc.x), clip50(acc.y), clip50(acc.z), clip50(acc.w));
  }
}

// ---------------- final conv (heads=1, C=4) -> d_out ----------------
__launch_bounds__(256)
__global__ void k_conv_final(const int* __restrict__ rowptr, const int* __restrict__ perm_src,
                             const float* __restrict__ q4, const float* __restrict__ k4,
                             const float* __restrict__ v4, const float* __restrict__ r4,
                             float* __restrict__ out) {
  int lane = threadIdx.x & 63;
  int wid = blockIdx.x * 4 + (threadIdx.x >> 6);
  int nw = gridDim.x * 4;
  for (int node = wid; node < NN; node += nw) {
    int beg = rowptr[node], end = rowptr[node + 1];
    float4 q = *(const float4*)(q4 + node * 4);
    float den = 0.f;
    float4 acc = make_float4(0, 0, 0, 0);
    for (int base = beg; base < end; base += 64) {
      int i = base + lane;
      bool act = i < end;
      int src = act ? perm_src[i] : 0;
      float4 kk = *(const float4*)(k4 + src * 4);
      float4 vv = *(const float4*)(v4 + src * 4);
      float p = q.x * kk.x + q.y * kk.y + q.z * kk.z + q.w * kk.w;
      float ex = act ? __expf(clip50(p * 0.5f)) : 0.f;
      den += ex;
      acc.x = fmaf(vv.x, ex, acc.x); acc.y = fmaf(vv.y, ex, acc.y);
      acc.z = fmaf(vv.z, ex, acc.z); acc.w = fmaf(vv.w, ex, acc.w);
    }
#pragma unroll
    for (int off = 1; off < 64; off <<= 1) {
      den += __shfl_xor(den, off);
      acc.x += __shfl_xor(acc.x, off); acc.y += __shfl_xor(acc.y, off);
      acc.z += __shfl_xor(acc.z, off); acc.w += __shfl_xor(acc.w, off);
    }
    if (lane == 0) {
      float inv = 1.f / (den + 1e-16f);
      float4 r = *(const float4*)(r4 + node * 4);
      *(float4*)(out + node * 4) = make_float4(
          fmaf(acc.x, inv, r.x), fmaf(acc.y, inv, r.y),
          fmaf(acc.z, inv, r.z), fmaf(acc.w, inv, r.w));
    }
  }
}

extern "C" void kernel_launch(void* const* d_in, const int* in_sizes, int n_in,
                              void* d_out, int out_size, void* d_ws, size_t ws_size,
                              hipStream_t stream) {
  const float* x = (const float*)d_in[0];
  const float* pWq = (const float*)d_in[1];
  const float* pWk = (const float*)d_in[2];
  const float* pWv = (const float*)d_in[3];
  const float* pWr = (const float*)d_in[4];
  const float* ln0_g = (const float*)d_in[5];
  const float* ln0_b = (const float*)d_in[6];
  const float* bn0_g = (const float*)d_in[7];
  const float* bn0_b = (const float*)d_in[8];
  const float* cWq = (const float*)d_in[9];
  const float* cWk = (const float*)d_in[10];
  const float* cWv = (const float*)d_in[11];
  const float* cWr = (const float*)d_in[12];
  const float* lns_g = (const float*)d_in[13];
  const float* lns_b = (const float*)d_in[14];
  const float* bns_g = (const float*)d_in[15];
  const float* bns_b = (const float*)d_in[16];
  const float* fWq = (const float*)d_in[17];
  const float* fWk = (const float*)d_in[18];
  const float* fWv = (const float*)d_in[19];
  const float* fWr = (const float*)d_in[20];
  const int* ei = (const int*)d_in[21];
  float* out = (float*)d_out;

  char* wsp = (char*)d_ws;
  size_t off = 0;
  auto carve = [&](size_t bytes) -> void* {
    void* p = wsp + off;
    off = (off + bytes + 255) & ~(size_t)255;
    return p;
  };
  int* rowptr = (int*)carve((NN + 1) * sizeof(int));
  int* deg = (int*)carve(NN * sizeof(int));
  int* fill = (int*)carve(NN * sizeof(int));
  int* btot = (int*)carve(64 * sizeof(int));
  int* perm_src = (int*)carve(NE * sizeof(int));
  __half* qh = (__half*)carve((size_t)NN * 128 * 2);
  __half* kv = (__half*)carve((size_t)NN * 256 * 2);
  __half* rh = (__half*)carve((size_t)NN * 128 * 2);
  __half* Ha = (__half*)carve((size_t)NN * 128 * 2);
  __half* Hb = (__half*)carve((size_t)NN * 128 * 2);
  __half* hact = (__half*)carve((size_t)NN * 128 * 2);
  float* q4 = (float*)carve((size_t)NN * 4 * 4);
  float* k4 = (float*)carve((size_t)NN * 4 * 4);
  float* v4 = (float*)carve((size_t)NN * 4 * 4);
  float* r4 = (float*)carve((size_t)NN * 4 * 4);
  float* bn_acc = (float*)carve(4 * 256 * 4);
  unsigned short* wt_hi = (unsigned short*)carve(212992 * sizeof(unsigned short));
  unsigned short* wt_lo = (unsigned short*)carve(212992 * sizeof(unsigned short));
  (void)ws_size; (void)in_sizes; (void)n_in; (void)out_size;

  // CSR build + weight prep
  k_zero<<<(NN + 255) / 256, 256, 0, stream>>>(deg, bn_acc);
  k_wprep<<<dim3(64, 16), 256, 0, stream>>>(pWq, pWk, pWv, pWr, cWq, cWk, cWv, cWr,
                                            wt_hi, wt_lo);
  k_hist<<<(NE + 255) / 256, 256, 0, stream>>>(ei, deg);
  const int NB_SCAN = (NN + 1023) / 1024;
  k_scan1<<<NB_SCAN, 1024, 0, stream>>>(deg, fill, btot);
  k_scan2<<<1, 64, 0, stream>>>(btot, NB_SCAN);
  k_scan3<<<(NN + 255) / 256, 256, 0, stream>>>(btot, fill, rowptr);
  k_scatter<<<(NE + 255) / 256, 256, 0, stream>>>(ei, fill, perm_src);

  const dim3 GEMM_GRID(256, 4);
  const int CONV_BLKS = 2048;

  // layer 0: x[N,32] -> qkv; conv0 -> hact, stats0
  k_gemm_lds<32, 0, float><<<GEMM_GRID, 256, 0, stream>>>(
      x, nullptr, nullptr, nullptr, nullptr, nullptr, wt_hi, qh, kv, rh);
  k_conv128<<<CONV_BLKS, 256, 0, stream>>>(rowptr, perm_src, qh, kv, rh, ln0_g, ln0_b,
                                           hact, bn_acc);

  // mid 0: A = bn0(hact0) (no res), writes Ha = h_in0 (fp16)
  k_gemm_lds<128, 1, __half><<<GEMM_GRID, 256, 0, stream>>>(
      hact, bn_acc, bn0_g, bn0_b, nullptr, Ha, wt_hi + 16384, qh, kv, rh);
  k_conv128<<<CONV_BLKS, 256, 0, stream>>>(rowptr, perm_src, qh, kv, rh, lns_g, lns_b,
                                           hact, bn_acc + 256);

  // mid 1: A = clip(bn(hact1)+Ha), writes Hb = h_mid0 (fp16)
  k_gemm_lds<128, 2, __half><<<GEMM_GRID, 256, 0, stream>>>(
      hact, bn_acc + 256, bns_g, bns_b, Ha, Hb, wt_hi + 16384 + 4 * 16384, qh, kv, rh);
  k_conv128<<<CONV_BLKS, 256, 0, stream>>>(rowptr, perm_src, qh, kv, rh, lns_g + 128,
                                           lns_b + 128, hact, bn_acc + 512);

  // mid 2: A = clip(bn(hact2)+Hb), writes Ha = h_mid1 (fp16)
  k_gemm_lds<128, 2, __half><<<GEMM_GRID, 256, 0, stream>>>(
      hact, bn_acc + 512, bns_g + 128, bns_b + 128, Hb, Ha, wt_hi + 16384 + 8 * 16384,
      qh, kv, rh);
  k_conv128<<<CONV_BLKS, 256, 0, stream>>>(rowptr, perm_src, qh, kv, rh, lns_g + 256,
                                           lns_b + 256, hact, bn_acc + 768);

  // final layer (heads=1, C=4): A = clip(bn(hact3)+Ha) fused; coef inline
  k_gemm_final<<<(NN + 31) / 32, 128, 0, stream>>>(hact, bn_acc + 768, bns_g + 256,
                                                   bns_b + 256, Ha, fWq, fWk, fWv, fWr,
                                                   q4, k4, v4, r4);
  k_conv_final<<<2048, 256, 0, stream>>>(rowptr, perm_src, q4, k4, v4, r4, out);
}

// Round 16
// 730.619 us; speedup vs baseline: 1.0071x; 1.0071x over previous
//
#include <hip/hip_runtime.h>
#include <hip/hip_fp16.h>
#include <math.h>

#define NN 50000
#define NE 600000
#define DIN 32
#define DD 128
#define NL 3
#define NC 4

__device__ __forceinline__ float clip50(float x) { return fminf(fmaxf(x, -50.f), 50.f); }

typedef __attribute__((ext_vector_type(8))) short bf16x8;
typedef __attribute__((ext_vector_type(4))) float f32x4;
typedef __attribute__((ext_vector_type(4))) unsigned int u32x4;

__device__ __forceinline__ unsigned short f2bf(float f) {
  unsigned u = __float_as_uint(f);
  return (unsigned short)((u + 0x7fffu + ((u >> 16) & 1u)) >> 16);
}

__device__ __forceinline__ float2 h2f2(unsigned int w) {
  __half2 h;
  *(unsigned int*)&h = w;
  return __half22float2(h);
}

__device__ __forceinline__ unsigned int f2h2(float a, float b) {
  __half2 h = __floats2half2_rn(a, b);
  return *(unsigned int*)&h;
}

// ---------------- CSR build ----------------
__global__ void k_hist(const int* __restrict__ ei, int* __restrict__ deg) {
  int e = blockIdx.x * blockDim.x + threadIdx.x;
  if (e < NE) atomicAdd(&deg[ei[NE + e]], 1);
}

__global__ void k_scan1(const int* __restrict__ deg, int* __restrict__ fill,
                        int* __restrict__ btot) {
  __shared__ int sd[1024];
  int tid = threadIdx.x;
  int i = blockIdx.x * 1024 + tid;
  int v = (i < NN) ? deg[i] : 0;
  sd[tid] = v;
  __syncthreads();
  for (int off = 1; off < 1024; off <<= 1) {
    int t = (tid >= off) ? sd[tid - off] : 0;
    __syncthreads();
    sd[tid] += t;
    __syncthreads();
  }
  if (i < NN) fill[i] = sd[tid] - v;  // block-local exclusive
  if (tid == 1023) btot[blockIdx.x] = sd[1023];
}

// scan3 with the 49-entry block-offset prefix computed locally in wave 0
// (removes the former 1-block k_scan2 dispatch + its serialization gap)
__global__ void k_scan3(const int* __restrict__ btot, int* __restrict__ fill,
                        int* __restrict__ rowptr, int nb) {
  __shared__ int sb[64];
  int tid = threadIdx.x;
  if (tid < 64) {
    int v = (tid < nb) ? btot[tid] : 0;
    int orig = v;
#pragma unroll
    for (int off = 1; off < 64; off <<= 1) {
      int t = __shfl_up(v, off, 64);
      if (tid >= off) v += t;
    }
    sb[tid] = v - orig;  // exclusive block offset
  }
  __syncthreads();
  int i = blockIdx.x * blockDim.x + threadIdx.x;
  if (i < NN) {
    int r = fill[i] + sb[i >> 10];
    rowptr[i] = r;
    fill[i] = r;
  }
  if (i == 0) rowptr[NN] = NE;
}

__global__ void k_scatter(const int* __restrict__ ei, int* __restrict__ fill,
                          int* __restrict__ perm_src) {
  int e = blockIdx.x * blockDim.x + threadIdx.x;
  if (e < NE) {
    int dst = ei[NE + e];
    int pos = atomicAdd(&fill[dst], 1);
    perm_src[pos] = ei[e];
  }
}

// ---------------- weight prep (+ fused deg/bn_acc zeroing in y==0 blocks) ----------------
__global__ void k_wprep(const float* __restrict__ pWq, const float* __restrict__ pWk,
                        const float* __restrict__ pWv, const float* __restrict__ pWr,
                        const float* __restrict__ cWq, const float* __restrict__ cWk,
                        const float* __restrict__ cWv, const float* __restrict__ cWr,
                        unsigned short* __restrict__ wh, unsigned short* __restrict__ wl,
                        int* __restrict__ deg, float* __restrict__ bn_acc) {
  int idx = blockIdx.x * 256 + threadIdx.x;
  if (blockIdx.y == 0) {  // fused k_zero (grid.x = 196 covers NN)
    if (idx < NN) deg[idx] = 0;
    if (idx < 4 * 256) bn_acc[idx] = 0.f;
  }
  int mat = blockIdx.y;
  int K = (mat < 4) ? 32 : 128;
  int nel = K * 128;
  if (idx >= nel) return;
  int k = idx >> 7;
  int col = idx & 127;
  int m = (mat < 4) ? mat : ((mat - 4) & 3);
  int layer = (mat < 4) ? 0 : ((mat - 4) >> 2);
  const float* base;
  if (mat < 4)
    base = (m == 0) ? pWq : (m == 1) ? pWk : (m == 2) ? pWv : pWr;
  else
    base = ((m == 0) ? cWq : (m == 1) ? cWk : (m == 2) ? cWv : cWr) + (size_t)layer * 16384;
  float f = base[idx];  // [k][col] row-major
  size_t off = (mat < 4) ? (size_t)mat * 4096 : 16384 + (size_t)(mat - 4) * 16384;
  unsigned short h = f2bf(f);
  float lo = f - __uint_as_float((unsigned)h << 16);
  wh[off + (size_t)col * K + k] = h;
  wl[off + (size_t)col * K + k] = f2bf(lo);
}

// ---------------- MFMA GEMM, ONE MATRIX PER BLOCK, B staged in LDS ----------------
// R14 3-pass split restored (R15's 2-pass was perf-neutral and cost 2x absmax):
// acc = Ahi*Bh + Alo*Bh + Ahi*Bl. BN coef inline from bn_acc.
// blockIdx.y = matrix m (0:q->fp16 + hwr(fp16), 1:k->kv.x, 2:v->kv.y, 3:r->fp16).
// MODE 0: A raw fp32. MODE 1: A' = bn(A). MODE 2: A' = clip(bn(A)+ident fp16).
template <int KD, int MODE, typename TA>
__launch_bounds__(256)
__global__ void k_gemm_lds(const TA* __restrict__ A,
                           const float* __restrict__ bn_acc,
                           const float* __restrict__ bng,
                           const float* __restrict__ bnb,
                           const __half* __restrict__ ident,
                           __half* __restrict__ hwr,
                           const unsigned short* __restrict__ WH,
                           const unsigned short* __restrict__ WL,
                           __half* __restrict__ Oq, __half* __restrict__ kv,
                           __half* __restrict__ Or) {
  constexpr int KS = KD / 32;
  constexpr int PK = KD + 8;
  constexpr int NTILES = (NN + 63) / 64;
  __shared__ unsigned short sBh[128 * PK];
  __shared__ unsigned short sBl[128 * PK];
  __shared__ float scoef[256];
  const int m = blockIdx.y;
  const unsigned short* wh = WH + (size_t)m * (KD * 128);
  const unsigned short* wl = WL + (size_t)m * (KD * 128);
  for (int idx = threadIdx.x * 8; idx < 128 * KD; idx += 256 * 8) {
    int col = idx / KD, k = idx - col * KD;
    *(u32x4*)(&sBh[col * PK + k]) = *(const u32x4*)(wh + idx);
    *(u32x4*)(&sBl[col * PK + k]) = *(const u32x4*)(wl + idx);
  }
  if constexpr (MODE > 0) {
    if (threadIdx.x < 128) {
      int c = threadIdx.x;
      float mean = bn_acc[c] * (1.f / NN);
      float var = bn_acc[128 + c] * (1.f / NN) - mean * mean;
      float sc = bng[c] * rsqrtf(var + 1e-5f);
      scoef[c] = sc;
      scoef[128 + c] = bnb[c] - mean * sc;
    }
  }
  __syncthreads();
  const int lane = threadIdx.x & 63;
  const int w = threadIdx.x >> 6;
  const int l15 = lane & 15;
  const int lhi = lane >> 4;
  for (int tile = blockIdx.x; tile < NTILES; tile += gridDim.x) {
    int row = tile * 64 + w * 16 + l15;
    bool rok = row < NN;
    int rowA = rok ? row : NN - 1;
    bf16x8 ahi[KS], alo[KS];
#pragma unroll
    for (int s = 0; s < KS; ++s) {
      int c0 = s * 32 + lhi * 8;
      float f[8];
      if constexpr (sizeof(TA) == 4) {
        const float* ap = (const float*)A + (size_t)rowA * KD + c0;
        float4 a0 = *(const float4*)(ap);
        float4 a1 = *(const float4*)(ap + 4);
        f[0] = a0.x; f[1] = a0.y; f[2] = a0.z; f[3] = a0.w;
        f[4] = a1.x; f[5] = a1.y; f[6] = a1.z; f[7] = a1.w;
      } else {
        const __half* ap = (const __half*)A + (size_t)rowA * KD + c0;
        u32x4 aw = *(const u32x4*)(ap);
#pragma unroll
        for (int j = 0; j < 4; ++j) {
          float2 t = h2f2(aw[j]);
          f[2 * j] = t.x;
          f[2 * j + 1] = t.y;
        }
      }
      if constexpr (MODE > 0) {
        float4 s0 = *(const float4*)(&scoef[c0]);
        float4 s1 = *(const float4*)(&scoef[c0 + 4]);
        float4 h0 = *(const float4*)(&scoef[128 + c0]);
        float4 h1 = *(const float4*)(&scoef[128 + c0 + 4]);
        float sc[8] = {s0.x, s0.y, s0.z, s0.w, s1.x, s1.y, s1.z, s1.w};
        float sh[8] = {h0.x, h0.y, h0.z, h0.w, h1.x, h1.y, h1.z, h1.w};
        if constexpr (MODE == 2) {
          const __half* ip = ident + (size_t)rowA * KD + c0;
          u32x4 iw = *(const u32x4*)(ip);
          float id[8];
#pragma unroll
          for (int j = 0; j < 4; ++j) {
            float2 t = h2f2(iw[j]);
            id[2 * j] = t.x;
            id[2 * j + 1] = t.y;
          }
#pragma unroll
          for (int j = 0; j < 8; ++j) f[j] = clip50(fmaf(f[j], sc[j], sh[j]) + id[j]);
        } else {
#pragma unroll
          for (int j = 0; j < 8; ++j) f[j] = fmaf(f[j], sc[j], sh[j]);
        }
        if (m == 0 && rok) {
          __half* hp = hwr + (size_t)row * KD + c0;
          u32x4 hw;
          hw[0] = f2h2(f[0], f[1]);
          hw[1] = f2h2(f[2], f[3]);
          hw[2] = f2h2(f[4], f[5]);
          hw[3] = f2h2(f[6], f[7]);
          *(u32x4*)(hp) = hw;
        }
      }
#pragma unroll
      for (int j = 0; j < 8; ++j) {
        unsigned short h = f2bf(f[j]);
        ahi[s][j] = (short)h;
        float lo = f[j] - __uint_as_float((unsigned)h << 16);
        alo[s][j] = (short)f2bf(lo);
      }
    }
#pragma unroll
    for (int ct = 0; ct < 8; ++ct) {
      f32x4 acc = {0.f, 0.f, 0.f, 0.f};
      int colB = ct * 16 + l15;
#pragma unroll
      for (int s = 0; s < KS; ++s) {
        int boff = colB * PK + s * 32 + lhi * 8;
        bf16x8 bh = *(const bf16x8*)(&sBh[boff]);
        bf16x8 bl = *(const bf16x8*)(&sBl[boff]);
        acc = __builtin_amdgcn_mfma_f32_16x16x32_bf16(ahi[s], bh, acc, 0, 0, 0);
        acc = __builtin_amdgcn_mfma_f32_16x16x32_bf16(alo[s], bh, acc, 0, 0, 0);
        acc = __builtin_amdgcn_mfma_f32_16x16x32_bf16(ahi[s], bl, acc, 0, 0, 0);
      }
      int rbase = tile * 64 + w * 16 + lhi * 4;
      if (m == 0 || m == 3) {
        __half* O = (m == 0) ? Oq : Or;
#pragma unroll
        for (int j = 0; j < 4; ++j) {
          int g = rbase + j;
          if (g < NN) O[(size_t)g * 128 + colB] = __float2half(clip50(acc[j]));
        }
      } else {
        int sub = m - 1;
#pragma unroll
        for (int j = 0; j < 4; ++j) {
          int g = rbase + j;
          if (g < NN)
            kv[((size_t)g * 128 + colB) * 2 + sub] = __float2half(clip50(acc[j]));
        }
      }
    }
  }
}

// ---------------- conv (heads=4, D=128) + LN + ReLU + BN partial stats ----------------
#define LDKV(i, off)                                            \
  u32x4 kv##i = {0, 0, 0, 0};                                   \
  if (cnt > (off)) {                                            \
    int s##i = __shfl(myidx, lbase + b + (off), 64);            \
    kv##i = *(const u32x4*)(kvp + (size_t)s##i * 256 + 8 * sl); \
  }

#define EDKV(i, off)                                                              \
  if (cnt > (off)) {                                                              \
    float2 c0 = h2f2(kv##i[0]), c1 = h2f2(kv##i[1]);                              \
    float2 c2 = h2f2(kv##i[2]), c3 = h2f2(kv##i[3]);                              \
    float p = c0.x * q4.x + c1.x * q4.y + c2.x * q4.z + c3.x * q4.w;              \
    p += __shfl_xor(p, 1); p += __shfl_xor(p, 2); p += __shfl_xor(p, 4);          \
    float ex = __expf(clip50(p * scale));                                         \
    denom += ex;                                                                  \
    acc.x = fmaf(c0.y, ex, acc.x); acc.y = fmaf(c1.y, ex, acc.y);                 \
    acc.z = fmaf(c2.y, ex, acc.z); acc.w = fmaf(c3.y, ex, acc.w);                 \
  }

__launch_bounds__(256)
__global__ void k_conv128(const int* __restrict__ rowptr, const int* __restrict__ perm_src,
                          const __half* __restrict__ qb, const __half* __restrict__ kvp,
                          const __half* __restrict__ rb,
                          const float* __restrict__ lng, const float* __restrict__ lnb,
                          __half* __restrict__ hact, float* __restrict__ bn_acc) {
  const float scale = 0.17677669529663687f;  // 32^-0.5
  __shared__ float s_bn[256];
  int tid = threadIdx.x;
  if (tid < 256) s_bn[tid] = 0.f;
  __syncthreads();
  int sl = tid & 31;
  int lbase = tid & 32;
  int grp = tid >> 5;
  int gid = blockIdx.x * 8 + grp;
  int ng = gridDim.x * 8;
  float bs[4] = {0, 0, 0, 0}, bq[4] = {0, 0, 0, 0};
  float4 g4 = *(const float4*)(lng + 4 * sl);
  float4 b4 = *(const float4*)(lnb + 4 * sl);
  for (int node = gid; node < NN; node += ng) {
    int beg = rowptr[node], end = rowptr[node + 1];
    uint2 qw = *(const uint2*)(qb + (size_t)node * 128 + 4 * sl);
    float2 qlo = h2f2(qw.x), qhi = h2f2(qw.y);
    float4 q4 = make_float4(qlo.x, qlo.y, qhi.x, qhi.y);
    float denom = 0.f;
    float4 acc = make_float4(0.f, 0.f, 0.f, 0.f);
    for (int chunk = beg; chunk < end; chunk += 32) {
      int m = min(32, end - chunk);
      int myidx = (chunk + sl < end) ? perm_src[chunk + sl] : 0;  // coalesced
      for (int b = 0; b < m; b += 8) {
        int cnt = m - b;  // uniform within group
        LDKV(0, 0)
        LDKV(1, 1)
        LDKV(2, 2)
        LDKV(3, 3)
        LDKV(4, 4)
        LDKV(5, 5)
        LDKV(6, 6)
        LDKV(7, 7)
        EDKV(0, 0)
        EDKV(1, 1)
        EDKV(2, 2)
        EDKV(3, 3)
        EDKV(4, 4)
        EDKV(5, 5)
        EDKV(6, 6)
        EDKV(7, 7)
      }
    }
    float inv = 1.f / (denom + 1e-16f);
    uint2 rw = *(const uint2*)(rb + (size_t)node * 128 + 4 * sl);
    float2 rlo = h2f2(rw.x), rhi = h2f2(rw.y);
    float ox = fmaf(acc.x, inv, rlo.x), oy = fmaf(acc.y, inv, rlo.y);
    float oz = fmaf(acc.z, inv, rhi.x), ow = fmaf(acc.w, inv, rhi.y);
    float s = ox + oy + oz + ow;
#pragma unroll
    for (int off = 1; off < 32; off <<= 1) s += __shfl_xor(s, off);
    float mu = s * (1.f / 128.f);
    float dx = ox - mu, dy = oy - mu, dz = oz - mu, dw = ow - mu;
    float vv = dx * dx + dy * dy + dz * dz + dw * dw;
#pragma unroll
    for (int off = 1; off < 32; off <<= 1) vv += __shfl_xor(vv, off);
    float rstd = rsqrtf(vv * (1.f / 128.f) + 1e-5f);
    float y0 = fmaxf(fmaf(dx * rstd, g4.x, b4.x), 0.f);
    float y1 = fmaxf(fmaf(dy * rstd, g4.y, b4.y), 0.f);
    float y2 = fmaxf(fmaf(dz * rstd, g4.z, b4.z), 0.f);
    float y3 = fmaxf(fmaf(dw * rstd, g4.w, b4.w), 0.f);
    uint2 ho;
    ho.x = f2h2(y0, y1);
    ho.y = f2h2(y2, y3);
    *(uint2*)(hact + (size_t)node * 128 + 4 * sl) = ho;
    bs[0] += y0; bq[0] += y0 * y0; bs[1] += y1; bq[1] += y1 * y1;
    bs[2] += y2; bq[2] += y2 * y2; bs[3] += y3; bq[3] += y3 * y3;
  }
#pragma unroll
  for (int j = 0; j < 4; ++j) {
    atomicAdd(&s_bn[4 * sl + j], bs[j]);
    atomicAdd(&s_bn[128 + 4 * sl + j], bq[j]);
  }
  __syncthreads();
  if (tid < 256) atomicAdd(&bn_acc[tid], s_bn[tid]);
}

// ---------------- final projection GEMM: inline BN coef + fused BN+res+clip ----------------
__launch_bounds__(128)
__global__ void k_gemm_final(const __half* __restrict__ hact,
                             const float* __restrict__ bn_acc,
                             const float* __restrict__ bng, const float* __restrict__ bnb,
                             const __half* __restrict__ ident,
                             const float* __restrict__ Wq, const float* __restrict__ Wk,
                             const float* __restrict__ Wv, const float* __restrict__ Wr,
                             float* __restrict__ Oq, float* __restrict__ Ok,
                             float* __restrict__ Ov, float* __restrict__ Or) {
  __shared__ float At[32 * 130];
  __shared__ float scoef[256];
  {
    int c = threadIdx.x;  // block is 128 threads
    float mean = bn_acc[c] * (1.f / NN);
    float var = bn_acc[128 + c] * (1.f / NN) - mean * mean;
    float sc = bng[c] * rsqrtf(var + 1e-5f);
    scoef[c] = sc;
    scoef[128 + c] = bnb[c] - mean * sc;
  }
  __syncthreads();
  int row0 = blockIdx.x * 32;
  for (int idx = threadIdx.x; idx < 32 * 128; idx += 128) {
    int r = idx >> 7, k = idx & 127;
    int gr = row0 + r;
    float v = 0.f;
    if (gr < NN) {
      v = clip50(fmaf(__half2float(hact[(size_t)gr * 128 + k]), scoef[k], scoef[128 + k]) +
                 __half2float(ident[(size_t)gr * 128 + k]));
    }
    At[r * 130 + k] = v;
  }
  __syncthreads();
  int r = threadIdx.x >> 2, m = threadIdx.x & 3;
  const float* W = (m == 0) ? Wq : (m == 1) ? Wk : (m == 2) ? Wv : Wr;
  float4 acc = make_float4(0, 0, 0, 0);
  const float* Ab = &At[r * 130];
  for (int k = 0; k < 128; ++k) {
    float a = Ab[k];
    float4 w = *(const float4*)(W + k * 4);
    acc.x = fmaf(a, w.x, acc.x); acc.y = fmaf(a, w.y, acc.y);
    acc.z = fmaf(a, w.z, acc.z); acc.w = fmaf(a, w.w, acc.w);
  }
  int gr = row0 + r;
  if (gr < NN) {
    float* O = (m == 0) ? Oq : (m == 1) ? Ok : (m == 2) ? Ov : Or;
    *(float4*)(O + gr * 4) =
        make_float4(clip50(acc.x), clip50(acc.y), clip50(acc.z), clip50(acc.w));
  }
}

// ---------------- final conv (heads=1, C=4) -> d_out ----------------
__launch_bounds__(256)
__global__ void k_conv_final(const int* __restrict__ rowptr, const int* __restrict__ perm_src,
                             const float* __restrict__ q4, const float* __restrict__ k4,
                             const float* __restrict__ v4, const float* __restrict__ r4,
                             float* __restrict__ out) {
  int lane = threadIdx.x & 63;
  int wid = blockIdx.x * 4 + (threadIdx.x >> 6);
  int nw = gridDim.x * 4;
  for (int node = wid; node < NN; node += nw) {
    int beg = rowptr[node], end = rowptr[node + 1];
    float4 q = *(const float4*)(q4 + node * 4);
    float den = 0.f;
    float4 acc = make_float4(0, 0, 0, 0);
    for (int base = beg; base < end; base += 64) {
      int i = base + lane;
      bool act = i < end;
      int src = act ? perm_src[i] : 0;
      float4 kk = *(const float4*)(k4 + src * 4);
      float4 vv = *(const float4*)(v4 + src * 4);
      float p = q.x * kk.x + q.y * kk.y + q.z * kk.z + q.w * kk.w;
      float ex = act ? __expf(clip50(p * 0.5f)) : 0.f;
      den += ex;
      acc.x = fmaf(vv.x, ex, acc.x); acc.y = fmaf(vv.y, ex, acc.y);
      acc.z = fmaf(vv.z, ex, acc.z); acc.w = fmaf(vv.w, ex, acc.w);
    }
#pragma unroll
    for (int off = 1; off < 64; off <<= 1) {
      den += __shfl_xor(den, off);
      acc.x += __shfl_xor(acc.x, off); acc.y += __shfl_xor(acc.y, off);
      acc.z += __shfl_xor(acc.z, off); acc.w += __shfl_xor(acc.w, off);
    }
    if (lane == 0) {
      float inv = 1.f / (den + 1e-16f);
      float4 r = *(const float4*)(r4 + node * 4);
      *(float4*)(out + node * 4) = make_float4(
          fmaf(acc.x, inv, r.x), fmaf(acc.y, inv, r.y),
          fmaf(acc.z, inv, r.z), fmaf(acc.w, inv, r.w));
    }
  }
}

extern "C" void kernel_launch(void* const* d_in, const int* in_sizes, int n_in,
                              void* d_out, int out_size, void* d_ws, size_t ws_size,
                              hipStream_t stream) {
  const float* x = (const float*)d_in[0];
  const float* pWq = (const float*)d_in[1];
  const float* pWk = (const float*)d_in[2];
  const float* pWv = (const float*)d_in[3];
  const float* pWr = (const float*)d_in[4];
  const float* ln0_g = (const float*)d_in[5];
  const float* ln0_b = (const float*)d_in[6];
  const float* bn0_g = (const float*)d_in[7];
  const float* bn0_b = (const float*)d_in[8];
  const float* cWq = (const float*)d_in[9];
  const float* cWk = (const float*)d_in[10];
  const float* cWv = (const float*)d_in[11];
  const float* cWr = (const float*)d_in[12];
  const float* lns_g = (const float*)d_in[13];
  const float* lns_b = (const float*)d_in[14];
  const float* bns_g = (const float*)d_in[15];
  const float* bns_b = (const float*)d_in[16];
  const float* fWq = (const float*)d_in[17];
  const float* fWk = (const float*)d_in[18];
  const float* fWv = (const float*)d_in[19];
  const float* fWr = (const float*)d_in[20];
  const int* ei = (const int*)d_in[21];
  float* out = (float*)d_out;

  char* wsp = (char*)d_ws;
  size_t off = 0;
  auto carve = [&](size_t bytes) -> void* {
    void* p = wsp + off;
    off = (off + bytes + 255) & ~(size_t)255;
    return p;
  };
  int* rowptr = (int*)carve((NN + 1) * sizeof(int));
  int* deg = (int*)carve(NN * sizeof(int));
  int* fill = (int*)carve(NN * sizeof(int));
  int* btot = (int*)carve(64 * sizeof(int));
  int* perm_src = (int*)carve(NE * sizeof(int));
  __half* qh = (__half*)carve((size_t)NN * 128 * 2);
  __half* kv = (__half*)carve((size_t)NN * 256 * 2);
  __half* rh = (__half*)carve((size_t)NN * 128 * 2);
  __half* Ha = (__half*)carve((size_t)NN * 128 * 2);
  __half* Hb = (__half*)carve((size_t)NN * 128 * 2);
  __half* hact = (__half*)carve((size_t)NN * 128 * 2);
  float* q4 = (float*)carve((size_t)NN * 4 * 4);
  float* k4 = (float*)carve((size_t)NN * 4 * 4);
  float* v4 = (float*)carve((size_t)NN * 4 * 4);
  float* r4 = (float*)carve((size_t)NN * 4 * 4);
  float* bn_acc = (float*)carve(4 * 256 * 4);
  unsigned short* wt_hi = (unsigned short*)carve(212992 * sizeof(unsigned short));
  unsigned short* wt_lo = (unsigned short*)carve(212992 * sizeof(unsigned short));
  (void)ws_size; (void)in_sizes; (void)n_in; (void)out_size;

  // weight prep + zeroing fused; CSR build (scan2 folded into scan3)
  k_wprep<<<dim3(196, 16), 256, 0, stream>>>(pWq, pWk, pWv, pWr, cWq, cWk, cWv, cWr,
                                             wt_hi, wt_lo, deg, bn_acc);
  k_hist<<<(NE + 255) / 256, 256, 0, stream>>>(ei, deg);
  const int NB_SCAN = (NN + 1023) / 1024;
  k_scan1<<<NB_SCAN, 1024, 0, stream>>>(deg, fill, btot);
  k_scan3<<<(NN + 255) / 256, 256, 0, stream>>>(btot, fill, rowptr, NB_SCAN);
  k_scatter<<<(NE + 255) / 256, 256, 0, stream>>>(ei, fill, perm_src);

  const dim3 GEMM_GRID(128, 4);
  const int CONV_BLKS = 2048;

  // layer 0: x[N,32] -> qkv; conv0 -> hact, stats0
  k_gemm_lds<32, 0, float><<<GEMM_GRID, 256, 0, stream>>>(
      x, nullptr, nullptr, nullptr, nullptr, nullptr, wt_hi, wt_lo, qh, kv, rh);
  k_conv128<<<CONV_BLKS, 256, 0, stream>>>(rowptr, perm_src, qh, kv, rh, ln0_g, ln0_b,
                                           hact, bn_acc);

  // mid 0: A = bn0(hact0) (no res), writes Ha = h_in0 (fp16)
  k_gemm_lds<128, 1, __half><<<GEMM_GRID, 256, 0, stream>>>(
      hact, bn_acc, bn0_g, bn0_b, nullptr, Ha, wt_hi + 16384, wt_lo + 16384, qh, kv, rh);
  k_conv128<<<CONV_BLKS, 256, 0, stream>>>(rowptr, perm_src, qh, kv, rh, lns_g, lns_b,
                                           hact, bn_acc + 256);

  // mid 1: A = clip(bn(hact1)+Ha), writes Hb = h_mid0 (fp16)
  k_gemm_lds<128, 2, __half><<<GEMM_GRID, 256, 0, stream>>>(
      hact, bn_acc + 256, bns_g, bns_b, Ha, Hb, wt_hi + 16384 + 4 * 16384,
      wt_lo + 16384 + 4 * 16384, qh, kv, rh);
  k_conv128<<<CONV_BLKS, 256, 0, stream>>>(rowptr, perm_src, qh, kv, rh, lns_g + 128,
                                           lns_b + 128, hact, bn_acc + 512);

  // mid 2: A = clip(bn(hact2)+Hb), writes Ha = h_mid1 (fp16)
  k_gemm_lds<128, 2, __half><<<GEMM_GRID, 256, 0, stream>>>(
      hact, bn_acc + 512, bns_g + 128, bns_b + 128, Hb, Ha, wt_hi + 16384 + 8 * 16384,
      wt_lo + 16384 + 8 * 16384, qh, kv, rh);
  k_conv128<<<CONV_BLKS, 256, 0, stream>>>(rowptr, perm_src, qh, kv, rh, lns_g + 256,
                                           lns_b + 256, hact, bn_acc + 768);

  // final layer (heads=1, C=4): A = clip(bn(hact3)+Ha) fused; coef inline
  k_gemm_final<<<(NN + 31) / 32, 128, 0, stream>>>(hact, bn_acc + 768, bns_g + 256,
                                                   bns_b + 256, Ha, fWq, fWk, fWv, fWr,
                                                   q4, k4, v4, r4);
  k_conv_final<<<2048, 256, 0, stream>>>(rowptr, perm_src, q4, k4, v4, r4, out);
}

// Round 18
// 729.834 us; speedup vs baseline: 1.0082x; 1.0011x over previous
//
#include <hip/hip_runtime.h>
#include <hip/hip_fp16.h>
#include <math.h>

#define NN 50000
#define NE 600000
#define DIN 32
#define DD 128
#define NL 3
#define NC 4

__device__ __forceinline__ float clip50(float x) { return fminf(fmaxf(x, -50.f), 50.f); }

typedef __attribute__((ext_vector_type(8))) short bf16x8;
typedef __attribute__((ext_vector_type(4))) float f32x4;
typedef __attribute__((ext_vector_type(4))) unsigned int u32x4;

__device__ __forceinline__ unsigned short f2bf(float f) {
  unsigned u = __float_as_uint(f);
  return (unsigned short)((u + 0x7fffu + ((u >> 16) & 1u)) >> 16);
}

__device__ __forceinline__ float2 h2f2(unsigned int w) {
  __half2 h;
  *(unsigned int*)&h = w;
  return __half22float2(h);
}

__device__ __forceinline__ unsigned int f2h2(float a, float b) {
  __half2 h = __floats2half2_rn(a, b);
  return *(unsigned int*)&h;
}

// ---------------- CSR build ----------------
__global__ void k_hist(const int* __restrict__ ei, int* __restrict__ deg) {
  int e = blockIdx.x * blockDim.x + threadIdx.x;
  if (e < NE) atomicAdd(&deg[ei[NE + e]], 1);
}

__global__ void k_scan1(const int* __restrict__ deg, int* __restrict__ fill,
                        int* __restrict__ btot) {
  __shared__ int sd[1024];
  int tid = threadIdx.x;
  int i = blockIdx.x * 1024 + tid;
  int v = (i < NN) ? deg[i] : 0;
  sd[tid] = v;
  __syncthreads();
  for (int off = 1; off < 1024; off <<= 1) {
    int t = (tid >= off) ? sd[tid - off] : 0;
    __syncthreads();
    sd[tid] += t;
    __syncthreads();
  }
  if (i < NN) fill[i] = sd[tid] - v;  // block-local exclusive
  if (tid == 1023) btot[blockIdx.x] = sd[1023];
}

// scan3 with the 49-entry block-offset prefix computed locally in wave 0
__global__ void k_scan3(const int* __restrict__ btot, int* __restrict__ fill,
                        int* __restrict__ rowptr, int nb) {
  __shared__ int sb[64];
  int tid = threadIdx.x;
  if (tid < 64) {
    int v = (tid < nb) ? btot[tid] : 0;
    int orig = v;
#pragma unroll
    for (int off = 1; off < 64; off <<= 1) {
      int t = __shfl_up(v, off, 64);
      if (tid >= off) v += t;
    }
    sb[tid] = v - orig;  // exclusive block offset
  }
  __syncthreads();
  int i = blockIdx.x * blockDim.x + threadIdx.x;
  if (i < NN) {
    int r = fill[i] + sb[i >> 10];
    rowptr[i] = r;
    fill[i] = r;
  }
  if (i == 0) rowptr[NN] = NE;
}

__global__ void k_scatter(const int* __restrict__ ei, int* __restrict__ fill,
                          int* __restrict__ perm_src) {
  int e = blockIdx.x * blockDim.x + threadIdx.x;
  if (e < NE) {
    int dst = ei[NE + e];
    int pos = atomicAdd(&fill[dst], 1);
    perm_src[pos] = ei[e];
  }
}

// ---------------- weight prep (+ fused deg/bn_acc zeroing in y==0 blocks) ----------------
__global__ void k_wprep(const float* __restrict__ pWq, const float* __restrict__ pWk,
                        const float* __restrict__ pWv, const float* __restrict__ pWr,
                        const float* __restrict__ cWq, const float* __restrict__ cWk,
                        const float* __restrict__ cWv, const float* __restrict__ cWr,
                        unsigned short* __restrict__ wh, unsigned short* __restrict__ wl,
                        int* __restrict__ deg, float* __restrict__ bn_acc) {
  int idx = blockIdx.x * 256 + threadIdx.x;
  if (blockIdx.y == 0) {  // fused k_zero (grid.x = 196 covers NN)
    if (idx < NN) deg[idx] = 0;
    if (idx < 4 * 256) bn_acc[idx] = 0.f;
  }
  int mat = blockIdx.y;
  int K = (mat < 4) ? 32 : 128;
  int nel = K * 128;
  if (idx >= nel) return;
  int k = idx >> 7;
  int col = idx & 127;
  int m = (mat < 4) ? mat : ((mat - 4) & 3);
  int layer = (mat < 4) ? 0 : ((mat - 4) >> 2);
  const float* base;
  if (mat < 4)
    base = (m == 0) ? pWq : (m == 1) ? pWk : (m == 2) ? pWv : pWr;
  else
    base = ((m == 0) ? cWq : (m == 1) ? cWk : (m == 2) ? cWv : cWr) + (size_t)layer * 16384;
  float f = base[idx];  // [k][col] row-major
  size_t off = (mat < 4) ? (size_t)mat * 4096 : 16384 + (size_t)(mat - 4) * 16384;
  unsigned short h = f2bf(f);
  float lo = f - __uint_as_float((unsigned)h << 16);
  wh[off + (size_t)col * K + k] = h;
  wl[off + (size_t)col * K + k] = f2bf(lo);
}

// ---------------- MFMA GEMM, ONE MATRIX PER BLOCK, B staged in LDS ----------------
// 3-pass split: acc = Ahi*Bh + Alo*Bh + Ahi*Bl. BN coef inline from bn_acc.
// blockIdx.y = matrix m (0:q->fp16 + hwr(fp16), 1:k->kv.x, 2:v->kv.y, 3:r->fp16).
// MODE 0: A raw fp32. MODE 1: A' = bn(A). MODE 2: A' = clip(bn(A)+ident fp16).
template <int KD, int MODE, typename TA>
__launch_bounds__(256)
__global__ void k_gemm_lds(const TA* __restrict__ A,
                           const float* __restrict__ bn_acc,
                           const float* __restrict__ bng,
                           const float* __restrict__ bnb,
                           const __half* __restrict__ ident,
                           __half* __restrict__ hwr,
                           const unsigned short* __restrict__ WH,
                           const unsigned short* __restrict__ WL,
                           __half* __restrict__ Oq, __half* __restrict__ kv,
                           __half* __restrict__ Or) {
  constexpr int KS = KD / 32;
  constexpr int PK = KD + 8;
  constexpr int NTILES = (NN + 63) / 64;
  __shared__ unsigned short sBh[128 * PK];
  __shared__ unsigned short sBl[128 * PK];
  __shared__ float scoef[256];
  const int m = blockIdx.y;
  const unsigned short* wh = WH + (size_t)m * (KD * 128);
  const unsigned short* wl = WL + (size_t)m * (KD * 128);
  for (int idx = threadIdx.x * 8; idx < 128 * KD; idx += 256 * 8) {
    int col = idx / KD, k = idx - col * KD;
    *(u32x4*)(&sBh[col * PK + k]) = *(const u32x4*)(wh + idx);
    *(u32x4*)(&sBl[col * PK + k]) = *(const u32x4*)(wl + idx);
  }
  if constexpr (MODE > 0) {
    if (threadIdx.x < 128) {
      int c = threadIdx.x;
      float mean = bn_acc[c] * (1.f / NN);
      float var = bn_acc[128 + c] * (1.f / NN) - mean * mean;
      float sc = bng[c] * rsqrtf(var + 1e-5f);
      scoef[c] = sc;
      scoef[128 + c] = bnb[c] - mean * sc;
    }
  }
  __syncthreads();
  const int lane = threadIdx.x & 63;
  const int w = threadIdx.x >> 6;
  const int l15 = lane & 15;
  const int lhi = lane >> 4;
  for (int tile = blockIdx.x; tile < NTILES; tile += gridDim.x) {
    int row = tile * 64 + w * 16 + l15;
    bool rok = row < NN;
    int rowA = rok ? row : NN - 1;
    bf16x8 ahi[KS], alo[KS];
#pragma unroll
    for (int s = 0; s < KS; ++s) {
      int c0 = s * 32 + lhi * 8;
      float f[8];
      if constexpr (sizeof(TA) == 4) {
        const float* ap = (const float*)A + (size_t)rowA * KD + c0;
        float4 a0 = *(const float4*)(ap);
        float4 a1 = *(const float4*)(ap + 4);
        f[0] = a0.x; f[1] = a0.y; f[2] = a0.z; f[3] = a0.w;
        f[4] = a1.x; f[5] = a1.y; f[6] = a1.z; f[7] = a1.w;
      } else {
        const __half* ap = (const __half*)A + (size_t)rowA * KD + c0;
        u32x4 aw = *(const u32x4*)(ap);
#pragma unroll
        for (int j = 0; j < 4; ++j) {
          float2 t = h2f2(aw[j]);
          f[2 * j] = t.x;
          f[2 * j + 1] = t.y;
        }
      }
      if constexpr (MODE > 0) {
        float4 s0 = *(const float4*)(&scoef[c0]);
        float4 s1 = *(const float4*)(&scoef[c0 + 4]);
        float4 h0 = *(const float4*)(&scoef[128 + c0]);
        float4 h1 = *(const float4*)(&scoef[128 + c0 + 4]);
        float sc[8] = {s0.x, s0.y, s0.z, s0.w, s1.x, s1.y, s1.z, s1.w};
        float sh[8] = {h0.x, h0.y, h0.z, h0.w, h1.x, h1.y, h1.z, h1.w};
        if constexpr (MODE == 2) {
          const __half* ip = ident + (size_t)rowA * KD + c0;
          u32x4 iw = *(const u32x4*)(ip);
          float id[8];
#pragma unroll
          for (int j = 0; j < 4; ++j) {
            float2 t = h2f2(iw[j]);
            id[2 * j] = t.x;
            id[2 * j + 1] = t.y;
          }
#pragma unroll
          for (int j = 0; j < 8; ++j) f[j] = clip50(fmaf(f[j], sc[j], sh[j]) + id[j]);
        } else {
#pragma unroll
          for (int j = 0; j < 8; ++j) f[j] = fmaf(f[j], sc[j], sh[j]);
        }
        if (m == 0 && rok) {
          __half* hp = hwr + (size_t)row * KD + c0;
          u32x4 hw;
          hw[0] = f2h2(f[0], f[1]);
          hw[1] = f2h2(f[2], f[3]);
          hw[2] = f2h2(f[4], f[5]);
          hw[3] = f2h2(f[6], f[7]);
          *(u32x4*)(hp) = hw;
        }
      }
#pragma unroll
      for (int j = 0; j < 8; ++j) {
        unsigned short h = f2bf(f[j]);
        ahi[s][j] = (short)h;
        float lo = f[j] - __uint_as_float((unsigned)h << 16);
        alo[s][j] = (short)f2bf(lo);
      }
    }
#pragma unroll
    for (int ct = 0; ct < 8; ++ct) {
      f32x4 acc = {0.f, 0.f, 0.f, 0.f};
      int colB = ct * 16 + l15;
#pragma unroll
      for (int s = 0; s < KS; ++s) {
        int boff = colB * PK + s * 32 + lhi * 8;
        bf16x8 bh = *(const bf16x8*)(&sBh[boff]);
        bf16x8 bl = *(const bf16x8*)(&sBl[boff]);
        acc = __builtin_amdgcn_mfma_f32_16x16x32_bf16(ahi[s], bh, acc, 0, 0, 0);
        acc = __builtin_amdgcn_mfma_f32_16x16x32_bf16(alo[s], bh, acc, 0, 0, 0);
        acc = __builtin_amdgcn_mfma_f32_16x16x32_bf16(ahi[s], bl, acc, 0, 0, 0);
      }
      int rbase = tile * 64 + w * 16 + lhi * 4;
      if (m == 0 || m == 3) {
        __half* O = (m == 0) ? Oq : Or;
#pragma unroll
        for (int j = 0; j < 4; ++j) {
          int g = rbase + j;
          if (g < NN) O[(size_t)g * 128 + colB] = __float2half(clip50(acc[j]));
        }
      } else {
        int sub = m - 1;
#pragma unroll
        for (int j = 0; j < 4; ++j) {
          int g = rbase + j;
          if (g < NN)
            kv[((size_t)g * 128 + colB) * 2 + sub] = __float2half(clip50(acc[j]));
        }
      }
    }
  }
}

// ---------------- conv (heads=4, D=128) + LN + ReLU + BN partial stats ----------------
#define LDKV(i, off)                                            \
  u32x4 kv##i = {0, 0, 0, 0};                                   \
  if (cnt > (off)) {                                            \
    int s##i = __shfl(myidx, lbase + b + (off), 64);            \
    kv##i = *(const u32x4*)(kvp + (size_t)s##i * 256 + 8 * sl); \
  }

#define EDKV(i, off)                                                              \
  if (cnt > (off)) {                                                              \
    float2 c0 = h2f2(kv##i[0]), c1 = h2f2(kv##i[1]);                              \
    float2 c2 = h2f2(kv##i[2]), c3 = h2f2(kv##i[3]);                              \
    float p = c0.x * q4.x + c1.x * q4.y + c2.x * q4.z + c3.x * q4.w;              \
    p += __shfl_xor(p, 1); p += __shfl_xor(p, 2); p += __shfl_xor(p, 4);          \
    float ex = __expf(clip50(p * scale));                                         \
    denom += ex;                                                                  \
    acc.x = fmaf(c0.y, ex, acc.x); acc.y = fmaf(c1.y, ex, acc.y);                 \
    acc.z = fmaf(c2.y, ex, acc.z); acc.w = fmaf(c3.y, ex, acc.w);                 \
  }

__launch_bounds__(256)
__global__ void k_conv128(const int* __restrict__ rowptr, const int* __restrict__ perm_src,
                          const __half* __restrict__ qb, const __half* __restrict__ kvp,
                          const __half* __restrict__ rb,
                          const float* __restrict__ lng, const float* __restrict__ lnb,
                          __half* __restrict__ hact, float* __restrict__ bn_acc) {
  const float scale = 0.17677669529663687f;  // 32^-0.5
  __shared__ float s_bn[256];
  int tid = threadIdx.x;
  if (tid < 256) s_bn[tid] = 0.f;
  __syncthreads();
  int sl = tid & 31;
  int lbase = tid & 32;
  int grp = tid >> 5;
  int gid = blockIdx.x * 8 + grp;
  int ng = gridDim.x * 8;
  float bs[4] = {0, 0, 0, 0}, bq[4] = {0, 0, 0, 0};
  float4 g4 = *(const float4*)(lng + 4 * sl);
  float4 b4 = *(const float4*)(lnb + 4 * sl);
  for (int node = gid; node < NN; node += ng) {
    int beg = rowptr[node], end = rowptr[node + 1];
    uint2 qw = *(const uint2*)(qb + (size_t)node * 128 + 4 * sl);
    float2 qlo = h2f2(qw.x), qhi = h2f2(qw.y);
    float4 q4 = make_float4(qlo.x, qlo.y, qhi.x, qhi.y);
    float denom = 0.f;
    float4 acc = make_float4(0.f, 0.f, 0.f, 0.f);
    for (int chunk = beg; chunk < end; chunk += 32) {
      int m = min(32, end - chunk);
      int myidx = (chunk + sl < end) ? perm_src[chunk + sl] : 0;  // coalesced
      for (int b = 0; b < m; b += 8) {
        int cnt = m - b;  // uniform within group
        LDKV(0, 0)
        LDKV(1, 1)
        LDKV(2, 2)
        LDKV(3, 3)
        LDKV(4, 4)
        LDKV(5, 5)
        LDKV(6, 6)
        LDKV(7, 7)
        EDKV(0, 0)
        EDKV(1, 1)
        EDKV(2, 2)
        EDKV(3, 3)
        EDKV(4, 4)
        EDKV(5, 5)
        EDKV(6, 6)
        EDKV(7, 7)
      }
    }
    float inv = 1.f / (denom + 1e-16f);
    uint2 rw = *(const uint2*)(rb + (size_t)node * 128 + 4 * sl);
    float2 rlo = h2f2(rw.x), rhi = h2f2(rw.y);
    float ox = fmaf(acc.x, inv, rlo.x), oy = fmaf(acc.y, inv, rlo.y);
    float oz = fmaf(acc.z, inv, rhi.x), ow = fmaf(acc.w, inv, rhi.y);
    float s = ox + oy + oz + ow;
#pragma unroll
    for (int off = 1; off < 32; off <<= 1) s += __shfl_xor(s, off);
    float mu = s * (1.f / 128.f);
    float dx = ox - mu, dy = oy - mu, dz = oz - mu, dw = ow - mu;
    float vv = dx * dx + dy * dy + dz * dz + dw * dw;
#pragma unroll
    for (int off = 1; off < 32; off <<= 1) vv += __shfl_xor(vv, off);
    float rstd = rsqrtf(vv * (1.f / 128.f) + 1e-5f);
    float y0 = fmaxf(fmaf(dx * rstd, g4.x, b4.x), 0.f);
    float y1 = fmaxf(fmaf(dy * rstd, g4.y, b4.y), 0.f);
    float y2 = fmaxf(fmaf(dz * rstd, g4.z, b4.z), 0.f);
    float y3 = fmaxf(fmaf(dw * rstd, g4.w, b4.w), 0.f);
    uint2 ho;
    ho.x = f2h2(y0, y1);
    ho.y = f2h2(y2, y3);
    *(uint2*)(hact + (size_t)node * 128 + 4 * sl) = ho;
    bs[0] += y0; bq[0] += y0 * y0; bs[1] += y1; bq[1] += y1 * y1;
    bs[2] += y2; bq[2] += y2 * y2; bs[3] += y3; bq[3] += y3 * y3;
  }
#pragma unroll
  for (int j = 0; j < 4; ++j) {
    atomicAdd(&s_bn[4 * sl + j], bs[j]);
    atomicAdd(&s_bn[128 + 4 * sl + j], bq[j]);
  }
  __syncthreads();
  if (tid < 256) atomicAdd(&bn_acc[tid], s_bn[tid]);
}

// ---------------- final projection GEMM: inline BN coef + fused BN+res+clip ----------------
__launch_bounds__(128)
__global__ void k_gemm_final(const __half* __restrict__ hact,
                             const float* __restrict__ bn_acc,
                             const float* __restrict__ bng, const float* __restrict__ bnb,
                             const __half* __restrict__ ident,
                             const float* __restrict__ Wq, const float* __restrict__ Wk,
                             const float* __restrict__ Wv, const float* __restrict__ Wr,
                             float* __restrict__ Oq, float* __restrict__ Ok,
                             float* __restrict__ Ov, float* __restrict__ Or) {
  __shared__ float At[32 * 130];
  __shared__ float scoef[256];
  {
    int c = threadIdx.x;  // block is 128 threads
    float mean = bn_acc[c] * (1.f / NN);
    float var = bn_acc[128 + c] * (1.f / NN) - mean * mean;
    float sc = bng[c] * rsqrtf(var + 1e-5f);
    scoef[c] = sc;
    scoef[128 + c] = bnb[c] - mean * sc;
  }
  __syncthreads();
  int row0 = blockIdx.x * 32;
  for (int idx = threadIdx.x; idx < 32 * 128; idx += 128) {
    int r = idx >> 7, k = idx & 127;
    int gr = row0 + r;
    float v = 0.f;
    if (gr < NN) {
      v = clip50(fmaf(__half2float(hact[(size_t)gr * 128 + k]), scoef[k], scoef[128 + k]) +
                 __half2float(ident[(size_t)gr * 128 + k]));
    }
    At[r * 130 + k] = v;
  }
  __syncthreads();
  int r = threadIdx.x >> 2, m = threadIdx.x & 3;
  const float* W = (m == 0) ? Wq : (m == 1) ? Wk : (m == 2) ? Wv : Wr;
  float4 acc = make_float4(0, 0, 0, 0);
  const float* Ab = &At[r * 130];
  for (int k = 0; k < 128; ++k) {
    float a = Ab[k];
    float4 w = *(const float4*)(W + k * 4);
    acc.x = fmaf(a, w.x, acc.x); acc.y = fmaf(a, w.y, acc.y);
    acc.z = fmaf(a, w.z, acc.z); acc.w = fmaf(a, w.w, acc.w);
  }
  int gr = row0 + r;
  if (gr < NN) {
    float* O = (m == 0) ? Oq : (m == 1) ? Ok : (m == 2) ? Ov : Or;
    *(float4*)(O + gr * 4) =
        make_float4(clip50(acc.x), clip50(acc.y), clip50(acc.z), clip50(acc.w));
  }
}

// ---------------- final conv (heads=1, C=4) -> d_out ----------------
__launch_bounds__(256)
__global__ void k_conv_final(const int* __restrict__ rowptr, const int* __restrict__ perm_src,
                             const float* __restrict__ q4, const float* __restrict__ k4,
                             const float* __restrict__ v4, const float* __restrict__ r4,
                             float* __restrict__ out) {
  int lane = threadIdx.x & 63;
  int wid = blockIdx.x * 4 + (threadIdx.x >> 6);
  int nw = gridDim.x * 4;
  for (int node = wid; node < NN; node += nw) {
    int beg = rowptr[node], end = rowptr[node + 1];
    float4 q = *(const float4*)(q4 + node * 4);
    float den = 0.f;
    float4 acc = make_float4(0, 0, 0, 0);
    for (int base = beg; base < end; base += 64) {
      int i = base + lane;
      bool act = i < end;
      int src = act ? perm_src[i] : 0;
      float4 kk = *(const float4*)(k4 + src * 4);
      float4 vv = *(const float4*)(v4 + src * 4);
      float p = q.x * kk.x + q.y * kk.y + q.z * kk.z + q.w * kk.w;
      float ex = act ? __expf(clip50(p * 0.5f)) : 0.f;
      den += ex;
      acc.x = fmaf(vv.x, ex, acc.x); acc.y = fmaf(vv.y, ex, acc.y);
      acc.z = fmaf(vv.z, ex, acc.z); acc.w = fmaf(vv.w, ex, acc.w);
    }
#pragma unroll
    for (int off = 1; off < 64; off <<= 1) {
      den += __shfl_xor(den, off);
      acc.x += __shfl_xor(acc.x, off); acc.y += __shfl_xor(acc.y, off);
      acc.z += __shfl_xor(acc.z, off); acc.w += __shfl_xor(acc.w, off);
    }
    if (lane == 0) {
      float inv = 1.f / (den + 1e-16f);
      float4 r = *(const float4*)(r4 + node * 4);
      *(float4*)(out + node * 4) = make_float4(
          fmaf(acc.x, inv, r.x), fmaf(acc.y, inv, r.y),
          fmaf(acc.z, inv, r.z), fmaf(acc.w, inv, r.w));
    }
  }
}

extern "C" void kernel_launch(void* const* d_in, const int* in_sizes, int n_in,
                              void* d_out, int out_size, void* d_ws, size_t ws_size,
                              hipStream_t stream) {
  const float* x = (const float*)d_in[0];
  const float* pWq = (const float*)d_in[1];
  const float* pWk = (const float*)d_in[2];
  const float* pWv = (const float*)d_in[3];
  const float* pWr = (const float*)d_in[4];
  const float* ln0_g = (const float*)d_in[5];
  const float* ln0_b = (const float*)d_in[6];
  const float* bn0_g = (const float*)d_in[7];
  const float* bn0_b = (const float*)d_in[8];
  const float* cWq = (const float*)d_in[9];
  const float* cWk = (const float*)d_in[10];
  const float* cWv = (const float*)d_in[11];
  const float* cWr = (const float*)d_in[12];
  const float* lns_g = (const float*)d_in[13];
  const float* lns_b = (const float*)d_in[14];
  const float* bns_g = (const float*)d_in[15];
  const float* bns_b = (const float*)d_in[16];
  const float* fWq = (const float*)d_in[17];
  const float* fWk = (const float*)d_in[18];
  const float* fWv = (const float*)d_in[19];
  const float* fWr = (const float*)d_in[20];
  const int* ei = (const int*)d_in[21];
  float* out = (float*)d_out;

  char* wsp = (char*)d_ws;
  size_t off = 0;
  auto carve = [&](size_t bytes) -> void* {
    void* p = wsp + off;
    off = (off + bytes + 255) & ~(size_t)255;
    return p;
  };
  int* rowptr = (int*)carve((NN + 1) * sizeof(int));
  int* deg = (int*)carve(NN * sizeof(int));
  int* fill = (int*)carve(NN * sizeof(int));
  int* btot = (int*)carve(64 * sizeof(int));
  int* perm_src = (int*)carve(NE * sizeof(int));
  __half* qh = (__half*)carve((size_t)NN * 128 * 2);
  __half* kv = (__half*)carve((size_t)NN * 256 * 2);
  __half* rh = (__half*)carve((size_t)NN * 128 * 2);
  __half* Ha = (__half*)carve((size_t)NN * 128 * 2);
  __half* Hb = (__half*)carve((size_t)NN * 128 * 2);
  __half* hact = (__half*)carve((size_t)NN * 128 * 2);
  float* q4 = (float*)carve((size_t)NN * 4 * 4);
  float* k4 = (float*)carve((size_t)NN * 4 * 4);
  float* v4 = (float*)carve((size_t)NN * 4 * 4);
  float* r4 = (float*)carve((size_t)NN * 4 * 4);
  float* bn_acc = (float*)carve(4 * 256 * 4);
  unsigned short* wt_hi = (unsigned short*)carve(212992 * sizeof(unsigned short));
  unsigned short* wt_lo = (unsigned short*)carve(212992 * sizeof(unsigned short));
  (void)ws_size; (void)in_sizes; (void)n_in; (void)out_size;

  // weight prep + zeroing fused; CSR build (scan2 folded into scan3)
  k_wprep<<<dim3(196, 16), 256, 0, stream>>>(pWq, pWk, pWv, pWr, cWq, cWk, cWv, cWr,
                                             wt_hi, wt_lo, deg, bn_acc);
  k_hist<<<(NE + 255) / 256, 256, 0, stream>>>(ei, deg);
  const int NB_SCAN = (NN + 1023) / 1024;
  k_scan1<<<NB_SCAN, 1024, 0, stream>>>(deg, fill, btot);
  k_scan3<<<(NN + 255) / 256, 256, 0, stream>>>(btot, fill, rowptr, NB_SCAN);
  k_scatter<<<(NE + 255) / 256, 256, 0, stream>>>(ei, fill, perm_src);

  const dim3 GEMM_GRID(128, 4);
  const int CONV_BLKS = 2048;

  // layer 0: x[N,32] -> qkv; conv0 -> hact, stats0
  k_gemm_lds<32, 0, float><<<GEMM_GRID, 256, 0, stream>>>(
      x, nullptr, nullptr, nullptr, nullptr, nullptr, wt_hi, wt_lo, qh, kv, rh);
  k_conv128<<<CONV_BLKS, 256, 0, stream>>>(rowptr, perm_src, qh, kv, rh, ln0_g, ln0_b,
                                           hact, bn_acc);

  // mid 0: A = bn0(hact0) (no res), writes Ha = h_in0 (fp16)
  k_gemm_lds<128, 1, __half><<<GEMM_GRID, 256, 0, stream>>>(
      hact, bn_acc, bn0_g, bn0_b, nullptr, Ha, wt_hi + 16384, wt_lo + 16384, qh, kv, rh);
  k_conv128<<<CONV_BLKS, 256, 0, stream>>>(rowptr, perm_src, qh, kv, rh, lns_g, lns_b,
                                           hact, bn_acc + 256);

  // mid 1: A = clip(bn(hact1)+Ha), writes Hb = h_mid0 (fp16)
  k_gemm_lds<128, 2, __half><<<GEMM_GRID, 256, 0, stream>>>(
      hact, bn_acc + 256, bns_g, bns_b, Ha, Hb, wt_hi + 16384 + 4 * 16384,
      wt_lo + 16384 + 4 * 16384, qh, kv, rh);
  k_conv128<<<CONV_BLKS, 256, 0, stream>>>(rowptr, perm_src, qh, kv, rh, lns_g + 128,
                                           lns_b + 128, hact, bn_acc + 512);

  // mid 2: A = clip(bn(hact2)+Hb), writes Ha = h_mid1 (fp16)
  k_gemm_lds<128, 2, __half><<<GEMM_GRID, 256, 0, stream>>>(
      hact, bn_acc + 512, bns_g + 128, bns_b + 128, Hb, Ha, wt_hi + 16384 + 8 * 16384,
      wt_lo + 16384 + 8 * 16384, qh, kv, rh);
  k_conv128<<<CONV_BLKS, 256, 0, stream>>>(rowptr, perm_src, qh, kv, rh, lns_g + 256,
                                           lns_b + 256, hact, bn_acc + 768);

  // final layer (heads=1, C=4): A = clip(bn(hact3)+Ha) fused; coef inline
  k_gemm_final<<<(NN + 31) / 32, 128, 0, stream>>>(hact, bn_acc + 768, bns_g + 256,
                                                   bns_b + 256, Ha, fWq, fWk, fWv, fWr,
                                                   q4, k4, v4, r4);
  k_conv_final<<<2048, 256, 0, stream>>>(rowptr, perm_src, q4, k4, v4, r4, out);
}